// Round 12
// baseline (145.959 us; speedup 1.0000x reference)
//
#include <hip/hip_runtime.h>
#include <hip/hip_bf16.h>

// MultiHeadAttention: B=4, T=2048, D=512, H=8, K=64.
// Inputs fp32, output fp32, intermediates bf16.
// [0] cvt_w: w_qkv -> bf16 (tiny, 1.5 MB)
// [1] gemm_bb: qkv projection, x read DIRECTLY as fp32 with inline bf16
//     conversion in the A-staging path (R23: cvt_all's x-pass fused away).
//     Q -> qb[8192][512]; K -> kT[b][h][s][d] (head-contiguous; R23: stores
//     remapped to 1KB/wave contiguous); V -> vT[b][h][d][perm(s)].
// [2] attn_v13: s-split 8-wave blocks, q=32/wave, swapped QK^T, in-register
//     P, lsum-by-MFMA, double-buffered LDS staging, head-contiguous K panel.
// [3] gemm_b64: out = attn @ w_proj^T + b_proj. LDS-staged epilogue.
//
// ws: qb 8 MiB + kT 8 MiB + vT 8 MiB + ao 8 MiB = 32 MiB.

typedef unsigned short u16;
typedef __attribute__((ext_vector_type(8))) __bf16 bf16x8;
typedef __attribute__((ext_vector_type(8))) unsigned short u16x8;
typedef __attribute__((ext_vector_type(4))) unsigned short u16x4;
typedef __attribute__((ext_vector_type(4))) float f32x4;
typedef __attribute__((ext_vector_type(4))) unsigned u32x4;
typedef __attribute__((ext_vector_type(2))) unsigned u32x2;

#define DEV static __device__ __forceinline__

DEV void async16(const u16* g, u16* l) {  // global->LDS DMA, 16B/lane
  __builtin_amdgcn_global_load_lds(
      (const __attribute__((address_space(1))) unsigned int*)g,
      (__attribute__((address_space(3))) unsigned int*)l, 16, 0, 0);
}
DEV u16x8 gld8(const u16* p) { return *(const u16x8*)p; }
DEV void lst8(u16* p, u16x8 v) { *(u16x8*)p = v; }
DEV bf16x8 ldsld8(const u16* p) {
  return __builtin_bit_cast(bf16x8, *(const u16x8*)p);
}
DEV f32x4 mfma16(bf16x8 a, bf16x8 b, f32x4 c) {
  return __builtin_amdgcn_mfma_f32_16x16x32_bf16(a, b, c, 0, 0, 0);
}
DEV u16 f2b(float f) {  // fp32 -> bf16 RNE (epilogue-only)
  unsigned u = __builtin_bit_cast(unsigned, f);
  u += 0x7FFFu + ((u >> 16) & 1u);
  return (u16)(u >> 16);
}
DEV unsigned pk2(float x, float y) {  // v_cvt_pk_bf16_f32: low=x, high=y
  __hip_bfloat162 t = __float22bfloat162_rn(float2{x, y});
  unsigned r;
  __builtin_memcpy(&r, &t, 4);
  return r;
}
DEV u16x8 pack8(f32x4 a, f32x4 b) {
  u32x4 t;
  t[0] = pk2(a[0], a[1]);
  t[1] = pk2(a[2], a[3]);
  t[2] = pk2(b[0], b[1]);
  t[3] = pk2(b[2], b[3]);
  return __builtin_bit_cast(u16x8, t);
}
// Raw workgroup barrier draining ONLY lgkmcnt (LDS ordering); global
// prefetch loads stay in flight.
DEV void barrier_lgkm() {
  asm volatile("s_waitcnt lgkmcnt(0)" ::: "memory");
  __builtin_amdgcn_s_barrier();
  asm volatile("" ::: "memory");
}

// ---------------------------------------------------------------------------
// fp32 -> bf16 for w_qkv only (1536x512); x conversion fused into gemm_bb.
__global__ void cvt_w(const float* __restrict__ wq, u16* __restrict__ wqb) {
  const long j = (long)blockIdx.x * 256 + threadIdx.x;  // 98304 threads exact
  const float* p = wq + j * 8;
  *(u16x8*)(wqb + j * 8) = pack8(*(const f32x4*)p, *(const f32x4*)(p + 4));
}

// ---------------------------------------------------------------------------
// gemm1: qkv projection. A = x[M,512] fp32 (converted inline during staging),
// Bt = wqb[1536,512] bf16. BM=BN=128, BK=64; B via async16 DMA; A via
// prefetched fp32 reg-staging + pack8 (gemm_b64's proven B-path pattern).
// XCD-swizzled grid. LDS-staged epilogues:
//   cols <512   -> qb[row][col] (LD=512), pre-scaled by 0.125*log2e
//   cols 512+   -> kT[(b*8+h)*2048 + s][d], 1KB/wave contiguous stores
//   cols 1024+  -> vT[(b*8+h)*64 + d][perm(s)] (within-32 s-perm)
// ---------------------------------------------------------------------------
__global__ void gemm_bb(const float* __restrict__ X, const u16* __restrict__ Bt,
                        u16* __restrict__ qb, u16* __restrict__ kT,
                        u16* __restrict__ vT, int K) {
  __shared__ __align__(16) u16 smem[17408];  // 34816 B
  auto As = (u16(*)[128 * 32])smem;          // As[2][4096]
  auto Bs = (u16(*)[128 * 32])(smem + 8192); // Bs[2][4096]
  u16* Cs = smem;                            // epilogue tile 128 x 136
  constexpr int LDC = 136;

  const int t = threadIdx.x, lane = t & 63, w = t >> 6;
  const int lane15 = lane & 15, quad = lane >> 4;
  const int wr = w >> 1, wc = w & 1;

  const int i = blockIdx.x;
  const int rt = (i & 7) | (((i >> 3) & 7) << 3);  // 0..63
  const int ct = i >> 6;                           // 0..11
  const long row0 = (long)rt * 128;
  const int col0 = ct * 128;

  const int srow = w * 16 + (lane >> 2);
  const int scol = (lane & 3) * 8;
  const float* Xg = X + (row0 + srow) * (long)K + scol;  // fp32 A source
  const u16* Bg = Bt + ((long)col0 + srow) * (long)K + scol;
  u16* AsD = &As[0][srow * 32 + scol];  // A staging dest (this thread)

  f32x4 acc[4][4];
#pragma unroll
  for (int ii = 0; ii < 4; ii++)
#pragma unroll
    for (int j = 0; j < 4; j++) acc[ii][j] = (f32x4)(0.0f);

  // A prefetch registers: [r*4 + hf*2 + half], 8 x f32x4
  f32x4 ax[8];
#pragma unroll
  for (int r = 0; r < 2; r++)
#pragma unroll
    for (int hf = 0; hf < 2; hf++) {
      ax[r * 4 + hf * 2] = *(const f32x4*)(Xg + (long)r * 64 * K + hf * 32);
      ax[r * 4 + hf * 2 + 1] =
          *(const f32x4*)(Xg + (long)r * 64 * K + hf * 32 + 4);
    }

  for (int k0 = 0; k0 < K; k0 += 64) {
    barrier_lgkm();  // prev LDS reads done; A fp32 prefetch stays in flight
#pragma unroll
    for (int r = 0; r < 2; r++)
#pragma unroll
      for (int hf = 0; hf < 2; hf++) {
        async16(Bg + (long)r * 64 * K + k0 + hf * 32,
                &Bs[hf][(r * 64 + w * 16) * 32]);
        lst8(AsD + hf * 4096 + r * 2048,
             pack8(ax[r * 4 + hf * 2], ax[r * 4 + hf * 2 + 1]));
      }
    __syncthreads();  // B DMA + A ds_writes complete

    {  // prefetch next k-tile's A (clamped)
      const int kp = (k0 + 64 < K) ? k0 + 64 : k0;
#pragma unroll
      for (int r = 0; r < 2; r++)
#pragma unroll
        for (int hf = 0; hf < 2; hf++) {
          ax[r * 4 + hf * 2] =
              *(const f32x4*)(Xg + (long)r * 64 * K + kp + hf * 32);
          ax[r * 4 + hf * 2 + 1] =
              *(const f32x4*)(Xg + (long)r * 64 * K + kp + hf * 32 + 4);
        }
    }

#pragma unroll
    for (int hf = 0; hf < 2; hf++) {
      bf16x8 a[4], b[4];
#pragma unroll
      for (int ii = 0; ii < 4; ii++)
        a[ii] = ldsld8(&As[hf][(wr * 64 + ii * 16 + lane15) * 32 + quad * 8]);
#pragma unroll
      for (int j = 0; j < 4; j++)
        b[j] = ldsld8(&Bs[hf][(wc * 64 + j * 16 + lane15) * 32 + quad * 8]);
#pragma unroll
      for (int ii = 0; ii < 4; ii++)
#pragma unroll
        for (int j = 0; j < 4; j++) acc[ii][j] = mfma16(a[ii], b[j], acc[ii][j]);
    }
  }

  __syncthreads();  // K-loop LDS reads done; reuse smem for C staging

  const long bb = row0 >> 11;          // batch
  const int s0g = (int)(row0 & 2047);  // s within batch

  if (col0 >= 1024) {
    // V part: stage TRANSPOSED (+ within-32 s-perm) -> Cs[d][perm(s_local)]
#pragma unroll
    for (int ii = 0; ii < 4; ii++)
#pragma unroll
      for (int j = 0; j < 4; j++) {
        const int d = wc * 64 + j * 16 + lane15;
        const int sl = wr * 64 + ii * 16 + quad * 4;
        const int psl =
            (sl & ~31) | (((sl >> 2) & 3) << 3) | (((sl >> 4) & 1) << 2);
        u32x2 pr;
        pr[0] = pk2(acc[ii][j][0], acc[ii][j][1]);
        pr[1] = pk2(acc[ii][j][2], acc[ii][j][3]);
        *(u16x4*)&Cs[d * LDC + psl] = __builtin_bit_cast(u16x4, pr);
      }
    __syncthreads();
    // coalesced: each vT d-row segment is 128 u16 = 256B contiguous
    const int rr = t >> 4, cc = (t & 15) * 8;
#pragma unroll
    for (int p = 0; p < 8; p++) {
      const int d = p * 16 + rr;
      *(u16x8*)(vT + ((bb * 512 + col0 - 1024 + d) * 2048L) + s0g + cc) =
          *(const u16x8*)&Cs[d * LDC + cc];
    }
  } else {
    // Q/K part: stage row-major bf16 (q tiles pre-scaled for attn's exp2)
    const bool isQ = (col0 < 512);
    const float sc = isQ ? 0.18033688f : 1.0f;
#pragma unroll
    for (int ii = 0; ii < 4; ii++)
#pragma unroll
      for (int j = 0; j < 4; j++) {
        const int c = wc * 64 + j * 16 + lane15;
#pragma unroll
        for (int r = 0; r < 4; r++) {
          const int rw = wr * 64 + ii * 16 + quad * 4 + r;
          Cs[rw * LDC + c] = f2b(acc[ii][j][r] * sc);
        }
      }
    __syncthreads();
    if (isQ) {
      // qb[row][col], LD=512; 256B wave segments
      const int rr = t >> 4, cc = (t & 15) * 8;
#pragma unroll
      for (int p = 0; p < 8; p++) {
        const int rw = p * 16 + rr;
        *(u16x8*)(qb + (row0 + rw) * 512L + col0 + cc) =
            *(const u16x8*)&Cs[rw * LDC + cc];
      }
    } else {
      // kT[(b*8 + h)*2048 + s][d]: head-contiguous K.
      // R23 remap: p selects (head half, 32-row group); 16 consecutive
      // threads cover 2 consecutive s-rows -> 1KB contiguous per wave.
      const int hbase = (col0 - 512) >> 6;
      const int rowp = t >> 3;        // 0..31
      const int cc8 = (t & 7) * 8;    // d-offset 0..56
#pragma unroll
      for (int p = 0; p < 8; p++) {
        const int head = hbase + (p >> 2);
        const int rw = (p & 3) * 32 + rowp;
        *(u16x8*)(kT + ((bb * 8 + head) * 2048L + s0g + rw) * 64 + cc8) =
            *(const u16x8*)&Cs[rw * LDC + (p >> 2) * 64 + cc8];
      }
    }
  }
}

// ---------------------------------------------------------------------------
// gemm3: C[M,512](fp32) = A[M,512](bf16) @ Bt[512,512](fp32)^T + bias.
// BM=128, BN=64, BK=64; XCD-swizzled. LDS-staged fp32 epilogue.
// ---------------------------------------------------------------------------
__global__ void gemm_b64(const u16* __restrict__ A, const float* __restrict__ Bt,
                         const float* __restrict__ bias, float* __restrict__ C,
                         int N, int K) {
  __shared__ __align__(16) u16 smem[17408];  // 34816 B
  auto As = (u16(*)[128 * 32])smem;          // As[2][4096]
  auto Bs = (u16(*)[64 * 32])(smem + 8192);  // Bs[2][2048]
  float* Cs = (float*)smem;                  // epilogue tile 128 x 68 f32
  constexpr int LDCF = 68;

  const int t = threadIdx.x, lane = t & 63, w = t >> 6;
  const int lane15 = lane & 15, quad = lane >> 4;
  const int wr = w >> 1, wc = w & 1;

  const int i = blockIdx.x;
  const int rt = (i & 7) | (((i >> 3) & 7) << 3);
  const int ct = i >> 6;
  const long row0 = (long)rt * 128;
  const int col0 = ct * 64;

  const int srow = w * 16 + (lane >> 2);
  const int scol = (lane & 3) * 8;
  const u16* Ag = A + (row0 + srow) * (long)K + scol;

  const int brow = t >> 2, bc = (t & 3) * 16;
  const float* Bg = Bt + (long)(col0 + brow) * K + bc;
  u16* BsD = &Bs[bc >> 5][brow * 32 + (bc & 31)];

  f32x4 acc[4][2];
#pragma unroll
  for (int ii = 0; ii < 4; ii++)
#pragma unroll
    for (int j = 0; j < 2; j++) acc[ii][j] = (f32x4)(0.0f);

  f32x4 q0 = *(const f32x4*)Bg, q1 = *(const f32x4*)(Bg + 4);
  f32x4 q2 = *(const f32x4*)(Bg + 8), q3 = *(const f32x4*)(Bg + 12);

  for (int k0 = 0; k0 < K; k0 += 64) {
    barrier_lgkm();  // prev LDS reads done; B-prefetch stays in flight
#pragma unroll
    for (int r = 0; r < 2; r++)
#pragma unroll
      for (int hf = 0; hf < 2; hf++)
        async16(Ag + (long)r * 64 * K + k0 + hf * 32,
                &As[hf][(r * 64 + w * 16) * 32]);
    lst8(BsD, pack8(q0, q1));
    lst8(BsD + 8, pack8(q2, q3));
    __syncthreads();  // DMA + ds_writes must be complete

    {
      const int kp = (k0 + 64 < K) ? k0 + 64 : k0;
      q0 = *(const f32x4*)(Bg + kp);     q1 = *(const f32x4*)(Bg + kp + 4);
      q2 = *(const f32x4*)(Bg + kp + 8); q3 = *(const f32x4*)(Bg + kp + 12);
    }

#pragma unroll
    for (int hf = 0; hf < 2; hf++) {
      bf16x8 a[4], b[2];
#pragma unroll
      for (int ii = 0; ii < 4; ii++)
        a[ii] = ldsld8(&As[hf][(wr * 64 + ii * 16 + lane15) * 32 + quad * 8]);
#pragma unroll
      for (int j = 0; j < 2; j++)
        b[j] = ldsld8(&Bs[hf][(wc * 32 + j * 16 + lane15) * 32 + quad * 8]);
#pragma unroll
      for (int ii = 0; ii < 4; ii++)
#pragma unroll
        for (int j = 0; j < 2; j++) acc[ii][j] = mfma16(a[ii], b[j], acc[ii][j]);
    }
  }

  __syncthreads();  // reuse smem for C staging
#pragma unroll
  for (int ii = 0; ii < 4; ii++)
#pragma unroll
    for (int j = 0; j < 2; j++) {
      const int c = wc * 32 + j * 16 + lane15;
      const float bv = bias[col0 + c];
#pragma unroll
      for (int r = 0; r < 4; r++) {
        const int rw = wr * 64 + ii * 16 + quad * 4 + r;
        Cs[rw * LDCF + c] = acc[ii][j][r] + bv;
      }
    }
  __syncthreads();
  const int rr = t >> 4, cc = (t & 15) * 4;
#pragma unroll
  for (int p = 0; p < 8; p++) {
    const int rw = p * 16 + rr;
    *(f32x4*)(C + (row0 + rw) * (long)N + col0 + cc) =
        *(const f32x4*)&Cs[rw * LDCF + cc];
  }
}

// ---------------------------------------------------------------------------
// attn_v13: 8-wave (512-thread) blocks over (b, h, 128-q); s-split halves.
// Per 4-wave group: own double-buffered K/V LDS, q=32/wave, swapped QK^T,
// in-register P (vT s-perm), lsum-by-MFMA, setprio. K tiles are 8 KB
// contiguous reads from the head-contiguous kT panel (L2-resident).
// End: half-1 dumps unnormalized O/lsum into dead K-buffer LDS; half-0
// adds, divides once, stores bf16 (pure-sum combine, no rescale).
// ---------------------------------------------------------------------------
__global__ void __launch_bounds__(512, 4)
attn_v13(const u16* __restrict__ Q, const u16* __restrict__ Kt,
         const u16* __restrict__ Vt, u16* __restrict__ out) {
  constexpr int T = 2048;
  __shared__ __align__(16) u16 Ks[2][2][64 * 72];  // [half][buf]
  __shared__ __align__(16) u16 Vs[2][2][64 * 72];

  const int t = threadIdx.x, lane = t & 63, w = t >> 6;
  const int lane15 = lane & 15, quad = lane >> 4;
  const int half = w >> 2, wl = w & 3;

  const int i = blockIdx.x;
  int qbi = i & 15;
  if (i >= 256) qbi = 15 - qbi;  // big+small block pairing
  const int h = (i >> 4) & 7;
  const int b = (i >> 7) & 3;
  const u16* kTb = Kt + ((long)b * 8 + h) * 2048 * 64;    // rows s, stride 64
  const u16* vTb = Vt + ((long)b * 512 + h * 64) * 2048;  // rows d, stride 2048

  // Q fragments for two 16-q strips (q = qbi*128 + wl*32 + {0,16} + lane15)
  const u16* gq =
      Q + ((long)b * T + qbi * 128 + wl * 32 + lane15) * 512 + h * 64 + quad * 8;
  const bf16x8 qa0 = __builtin_bit_cast(bf16x8, *(const u16x8*)gq);
  const bf16x8 qa1 = __builtin_bit_cast(bf16x8, *(const u16x8*)(gq + 32));
  const bf16x8 qc0 = __builtin_bit_cast(bf16x8, *(const u16x8*)(gq + 16 * 512));
  const bf16x8 qc1 =
      __builtin_bit_cast(bf16x8, *(const u16x8*)(gq + 16 * 512 + 32));

  const int th = t & 255;                        // thread within the half
  const int srow = th >> 3, sc8 = (th & 7) * 8;  // staging rows {srow, srow+32}
  const int nsbh = qbi + 1;                      // tiles per half
  const int s0 = half * nsbh;                    // first abs tile of this half
  const int sbd = 2 * qbi + (wl >> 1);           // wave's diagonal abs tile

  const u16* gk = kTb + (long)(s0 * 64 + srow) * 64 + sc8;  // 8KB contig tile
  const u16* gv = vTb + (long)srow * 2048 + s0 * 64 + sc8;

  u16x8 kr0, kr1, vr0, vr1;
  kr0 = gld8(gk); kr1 = gld8(gk + 32 * 64);
  vr0 = gld8(gv); vr1 = gld8(gv + (long)32 * 2048);
  lst8(&Ks[half][0][srow * 72 + sc8], kr0);
  lst8(&Ks[half][0][(srow + 32) * 72 + sc8], kr1);
  lst8(&Vs[half][0][srow * 72 + sc8], vr0);
  lst8(&Vs[half][0][(srow + 32) * 72 + sc8], vr1);
  if (nsbh > 1) { gk += 64 * 64; gv += 64; }
  kr0 = gld8(gk); kr1 = gld8(gk + 32 * 64);
  vr0 = gld8(gv); vr1 = gld8(gv + (long)32 * 2048);

  f32x4 o0[4], o1[4], lsum0 = (f32x4)(0.0f), lsum1 = (f32x4)(0.0f);
#pragma unroll
  for (int j = 0; j < 4; j++) { o0[j] = (f32x4)(0.0f); o1[j] = (f32x4)(0.0f); }

  const bf16x8 ones = __builtin_bit_cast(bf16x8, (u16x8)((u16)0x3F80));
  const int ql0 = ((wl & 1) << 5) + lane15;  // strip0 q, tile-local, on diag

  for (int it = 0; it < nsbh; ++it) {
    const u16* Kc = Ks[half][it & 1];
    const u16* Vc = Vs[half][it & 1];
    u16* Kn = Ks[half][(it + 1) & 1];
    u16* Vn = Vs[half][(it + 1) & 1];

    __syncthreads();  // buf[it&1] writes visible; buf[(it+1)&1] readers done

    // stage tile it+1 into the other buffer
    lst8(&Kn[srow * 72 + sc8], kr0);
    lst8(&Kn[(srow + 32) * 72 + sc8], kr1);
    lst8(&Vn[srow * 72 + sc8], vr0);
    lst8(&Vn[(srow + 32) * 72 + sc8], vr1);

    // prefetch tile it+2 (clamped) into regs
    if (it + 2 < nsbh) { gk += 64 * 64; gv += 64; }
    kr0 = gld8(gk); kr1 = gld8(gk + 32 * 64);
    vr0 = gld8(gv); vr1 = gld8(gv + (long)32 * 2048);

    const int sb = s0 + it;  // absolute s-tile
    if (sb <= sbd) {         // tiles past the wave's diagonal are fully masked
      __builtin_amdgcn_s_setprio(1);
      // S^T strips: K fragments feed both q-strips
      f32x4 sf0[4], sf1[4];
#pragma unroll
      for (int j = 0; j < 4; j++) {
        const bf16x8 k0 = ldsld8(&Kc[(j * 16 + lane15) * 72 + quad * 8]);
        const bf16x8 k1 = ldsld8(&Kc[(j * 16 + lane15) * 72 + quad * 8 + 32]);
        sf0[j] = mfma16(k1, qa1, mfma16(k0, qa0, (f32x4)(0.0f)));
        sf1[j] = mfma16(k1, qc1, mfma16(k0, qc0, (f32x4)(0.0f)));
      }

#pragma unroll
      for (int j = 0; j < 4; j++)
#pragma unroll
        for (int r = 0; r < 4; r++) {
          sf0[j][r] = exp2f(sf0[j][r]);
          sf1[j][r] = exp2f(sf1[j][r]);
        }
      if (sb == sbd) {  // causal zeroing, this wave's diagonal tile only
#pragma unroll
        for (int j = 0; j < 4; j++)
#pragma unroll
          for (int r = 0; r < 4; r++) {
            const int sl = j * 16 + quad * 4 + r;
            if (sl > ql0) sf0[j][r] = 0.0f;
            if (sl > ql0 + 16) sf1[j][r] = 0.0f;
          }
      }

      // pack P -> A-fragments in-register (k-order matches vT's s-perm)
      u32x4 w0, w1, w2, w3;
      w0[0] = pk2(sf0[0][0], sf0[0][1]); w0[1] = pk2(sf0[0][2], sf0[0][3]);
      w0[2] = pk2(sf0[1][0], sf0[1][1]); w0[3] = pk2(sf0[1][2], sf0[1][3]);
      w1[0] = pk2(sf0[2][0], sf0[2][1]); w1[1] = pk2(sf0[2][2], sf0[2][3]);
      w1[2] = pk2(sf0[3][0], sf0[3][1]); w1[3] = pk2(sf0[3][2], sf0[3][3]);
      w2[0] = pk2(sf1[0][0], sf1[0][1]); w2[1] = pk2(sf1[0][2], sf1[0][3]);
      w2[2] = pk2(sf1[1][0], sf1[1][1]); w2[3] = pk2(sf1[1][2], sf1[1][3]);
      w3[0] = pk2(sf1[2][0], sf1[2][1]); w3[1] = pk2(sf1[2][2], sf1[2][3]);
      w3[2] = pk2(sf1[3][0], sf1[3][1]); w3[3] = pk2(sf1[3][2], sf1[3][3]);
      const bf16x8 pa0 = __builtin_bit_cast(bf16x8, w0);
      const bf16x8 pa1 = __builtin_bit_cast(bf16x8, w1);
      const bf16x8 pc0 = __builtin_bit_cast(bf16x8, w2);
      const bf16x8 pc1 = __builtin_bit_cast(bf16x8, w3);

      // O += P @ V; V fragments feed both strips
#pragma unroll
      for (int j = 0; j < 4; j++) {
        const int d0 = (j * 16 + lane15) * 72;
        const bf16x8 v0 = ldsld8(&Vc[d0 + quad * 8]);
        const bf16x8 v1 = ldsld8(&Vc[d0 + quad * 8 + 32]);
        o0[j] = mfma16(pa1, v1, mfma16(pa0, v0, o0[j]));
        o1[j] = mfma16(pc1, v1, mfma16(pc0, v0, o1[j]));
      }
      // row-sums: C[m][*] = sum_k P[m][k]; lands at row m = quad*4+r
      lsum0 = mfma16(pa1, ones, mfma16(pa0, ones, lsum0));
      lsum1 = mfma16(pc1, ones, mfma16(pc0, ones, lsum1));
      __builtin_amdgcn_s_setprio(0);
    }
  }

  // -------- intra-block combine (pure sums; no rescale needed) --------
  __syncthreads();  // all K/V LDS reads done -> buffers reusable
  float* cmb = (float*)&Ks[0][0][0];  // 128 q x 64 d fp32 = 32 KB (fits in Ks)
  float* cl = (float*)&Vs[0][0][0];   // 128 fp32 row-sums

  if (half == 1) {
    const int q0 = wl * 32 + quad * 4;
#pragma unroll
    for (int j = 0; j < 4; j++)
#pragma unroll
      for (int r = 0; r < 4; r++) {
        cmb[(q0 + r) * 64 + j * 16 + lane15] = o0[j][r];
        cmb[(q0 + 16 + r) * 64 + j * 16 + lane15] = o1[j][r];
      }
    if (lane15 == 0) {
#pragma unroll
      for (int r = 0; r < 4; r++) {
        cl[q0 + r] = lsum0[r];
        cl[q0 + 16 + r] = lsum1[r];
      }
    }
  }
  __syncthreads();

  if (half == 0) {
    const int q0 = wl * 32 + quad * 4;
    f32x4 inv0, inv1;
#pragma unroll
    for (int r = 0; r < 4; r++) {
      inv0[r] = 1.0f / (lsum0[r] + cl[q0 + r]);
      inv1[r] = 1.0f / (lsum1[r] + cl[q0 + 16 + r]);
    }
    const long orow0 = (long)b * T + qbi * 128 + wl * 32;
#pragma unroll
    for (int j = 0; j < 4; j++)
#pragma unroll
      for (int r = 0; r < 4; r++) {
        const float a0 = o0[j][r] + cmb[(q0 + r) * 64 + j * 16 + lane15];
        const float a1 = o1[j][r] + cmb[(q0 + 16 + r) * 64 + j * 16 + lane15];
        const long rr = orow0 + quad * 4 + r;
        out[rr * 512 + h * 64 + j * 16 + lane15] = f2b(a0 * inv0[r]);
        out[(rr + 16) * 512 + h * 64 + j * 16 + lane15] = f2b(a1 * inv1[r]);
      }
  }
}

// ---------------------------------------------------------------------------
extern "C" void kernel_launch(void* const* d_in, const int* in_sizes, int n_in,
                              void* d_out, int out_size, void* d_ws, size_t ws_size,
                              hipStream_t stream) {
  const float* x      = (const float*)d_in[0];  // [4,2048,512] fp32
  const float* w_qkv  = (const float*)d_in[1];  // [1536,512]  fp32
  const float* w_proj = (const float*)d_in[2];  // [512,512]   fp32
  const float* b_proj = (const float*)d_in[3];  // [512]       fp32
  float* out = (float*)d_out;                   // [4,2048,512] fp32

  u16* qb = (u16*)d_ws;                   // [8192 x 512] bf16 = 8 MiB (Q)
  u16* kT = qb + (size_t)8192 * 512;      // [32 x 2048 x 64] bf16 = 8 MiB (K)
  u16* vT = kT + (size_t)32 * 2048 * 64;  // [32 x 64 x 2048] bf16 = 8 MiB (V^T)
  u16* ao = vT + (size_t)32 * 64 * 2048;  // [8192 x 512] bf16 = 8 MiB (attn out)
  u16* wqb = (u16*)d_out;                 // w_qkv bf16 parked in d_out

  // [0] convert w_qkv to bf16 (x conversion fused into gemm_bb)
  cvt_w<<<384, 256, 0, stream>>>(w_qkv, wqb);
  // [1] qkv projection: qb + head-contiguous kT + transposed/permuted vT
  gemm_bb<<<768, 256, 0, stream>>>(x, wqb, qb, kT, vT, 512);
  // [2] causal flash attention
  attn_v13<<<512, 512, 0, stream>>>(qb, kT, vT, ao);
  // [3] output projection + bias -> fp32 d_out
  gemm_b64<<<512, 256, 0, stream>>>(ao, w_proj, b_proj, out, 512, 512);
}

// Round 13
// 142.023 us; speedup vs baseline: 1.0277x; 1.0277x over previous
//
#include <hip/hip_runtime.h>
#include <hip/hip_bf16.h>

// MultiHeadAttention: B=4, T=2048, D=512, H=8, K=64.
// Inputs fp32, output fp32, intermediates bf16.
// R24 = R6 best config (142.58) + cvt-fusion only:
// [0] cvt_w: w_qkv -> bf16 (tiny)
// [1] gemm_bb: qkv projection; x read DIRECTLY as fp32, converted inline in
//     the A-staging path (R12-verified code). Outputs: qk[8192][1024]
//     (Q pre-scaled | K), vT[b][h][d][perm(s)]. LDS-staged epilogues (R6).
// [2] attn_v9 (R6-exact): s-split 8-wave blocks, q=32/wave, swapped QK^T,
//     in-register P, lsum-by-MFMA, double-buffered LDS, intra-block combine.
// [3] gemm_b64 (R6-exact): out = attn @ w_proj^T + b_proj, LDS epilogue.
//
// ws: qk 16 MiB + vT 8 MiB + ao 8 MiB = 32 MiB.

typedef unsigned short u16;
typedef __attribute__((ext_vector_type(8))) __bf16 bf16x8;
typedef __attribute__((ext_vector_type(8))) unsigned short u16x8;
typedef __attribute__((ext_vector_type(4))) unsigned short u16x4;
typedef __attribute__((ext_vector_type(4))) float f32x4;
typedef __attribute__((ext_vector_type(4))) unsigned u32x4;
typedef __attribute__((ext_vector_type(2))) unsigned u32x2;

#define DEV static __device__ __forceinline__

DEV void async16(const u16* g, u16* l) {  // global->LDS DMA, 16B/lane
  __builtin_amdgcn_global_load_lds(
      (const __attribute__((address_space(1))) unsigned int*)g,
      (__attribute__((address_space(3))) unsigned int*)l, 16, 0, 0);
}
DEV u16x8 gld8(const u16* p) { return *(const u16x8*)p; }
DEV void lst8(u16* p, u16x8 v) { *(u16x8*)p = v; }
DEV bf16x8 ldsld8(const u16* p) {
  return __builtin_bit_cast(bf16x8, *(const u16x8*)p);
}
DEV f32x4 mfma16(bf16x8 a, bf16x8 b, f32x4 c) {
  return __builtin_amdgcn_mfma_f32_16x16x32_bf16(a, b, c, 0, 0, 0);
}
DEV u16 f2b(float f) {  // fp32 -> bf16 RNE (epilogue-only)
  unsigned u = __builtin_bit_cast(unsigned, f);
  u += 0x7FFFu + ((u >> 16) & 1u);
  return (u16)(u >> 16);
}
DEV unsigned pk2(float x, float y) {  // v_cvt_pk_bf16_f32: low=x, high=y
  __hip_bfloat162 t = __float22bfloat162_rn(float2{x, y});
  unsigned r;
  __builtin_memcpy(&r, &t, 4);
  return r;
}
DEV u16x8 pack8(f32x4 a, f32x4 b) {
  u32x4 t;
  t[0] = pk2(a[0], a[1]);
  t[1] = pk2(a[2], a[3]);
  t[2] = pk2(b[0], b[1]);
  t[3] = pk2(b[2], b[3]);
  return __builtin_bit_cast(u16x8, t);
}
// Raw workgroup barrier draining ONLY lgkmcnt (LDS ordering); global
// prefetch loads stay in flight.
DEV void barrier_lgkm() {
  asm volatile("s_waitcnt lgkmcnt(0)" ::: "memory");
  __builtin_amdgcn_s_barrier();
  asm volatile("" ::: "memory");
}

// ---------------------------------------------------------------------------
// fp32 -> bf16 for w_qkv only (1536x512); x conversion fused into gemm_bb.
__global__ void cvt_w(const float* __restrict__ wq, u16* __restrict__ wqb) {
  const long j = (long)blockIdx.x * 256 + threadIdx.x;  // 98304 threads exact
  const float* p = wq + j * 8;
  *(u16x8*)(wqb + j * 8) = pack8(*(const f32x4*)p, *(const f32x4*)(p + 4));
}

// ---------------------------------------------------------------------------
// gemm1: qkv projection. A = x[M,512] fp32 (converted inline during staging),
// Bt = wqb[1536,512] bf16. BM=BN=128, BK=64; B via async16 DMA; A via
// prefetched fp32 reg-staging + pack8. XCD-swizzled grid.
// Epilogue (LDS-staged, R6 layout):
//   cols <1024  -> qk[row*1024 + col]; q cols (<512) scaled 0.125*log2e
//   cols >=1024 -> vT[(b*512 + d)*2048 + perm(s)] (within-32 s-perm)
// ---------------------------------------------------------------------------
__global__ void gemm_bb(const float* __restrict__ X, const u16* __restrict__ Bt,
                        u16* __restrict__ qk, u16* __restrict__ vT, int K) {
  __shared__ __align__(16) u16 smem[17408];  // 34816 B
  auto As = (u16(*)[128 * 32])smem;          // As[2][4096]
  auto Bs = (u16(*)[128 * 32])(smem + 8192); // Bs[2][4096]
  u16* Cs = smem;                            // epilogue tile 128 x 136
  constexpr int LDC = 136;

  const int t = threadIdx.x, lane = t & 63, w = t >> 6;
  const int lane15 = lane & 15, quad = lane >> 4;
  const int wr = w >> 1, wc = w & 1;

  const int i = blockIdx.x;
  const int rt = (i & 7) | (((i >> 3) & 7) << 3);  // 0..63
  const int ct = i >> 6;                           // 0..11
  const long row0 = (long)rt * 128;
  const int col0 = ct * 128;

  const int srow = w * 16 + (lane >> 2);
  const int scol = (lane & 3) * 8;
  const float* Xg = X + (row0 + srow) * (long)K + scol;  // fp32 A source
  const u16* Bg = Bt + ((long)col0 + srow) * (long)K + scol;
  u16* AsD = &As[0][srow * 32 + scol];  // A staging dest (this thread)

  f32x4 acc[4][4];
#pragma unroll
  for (int ii = 0; ii < 4; ii++)
#pragma unroll
    for (int j = 0; j < 4; j++) acc[ii][j] = (f32x4)(0.0f);

  // A prefetch registers: 8 x f32x4
  f32x4 ax[8];
#pragma unroll
  for (int r = 0; r < 2; r++)
#pragma unroll
    for (int hf = 0; hf < 2; hf++) {
      ax[r * 4 + hf * 2] = *(const f32x4*)(Xg + (long)r * 64 * K + hf * 32);
      ax[r * 4 + hf * 2 + 1] =
          *(const f32x4*)(Xg + (long)r * 64 * K + hf * 32 + 4);
    }

  for (int k0 = 0; k0 < K; k0 += 64) {
    barrier_lgkm();  // prev LDS reads done; A fp32 prefetch stays in flight
#pragma unroll
    for (int r = 0; r < 2; r++)
#pragma unroll
      for (int hf = 0; hf < 2; hf++) {
        async16(Bg + (long)r * 64 * K + k0 + hf * 32,
                &Bs[hf][(r * 64 + w * 16) * 32]);
        lst8(AsD + hf * 4096 + r * 2048,
             pack8(ax[r * 4 + hf * 2], ax[r * 4 + hf * 2 + 1]));
      }
    __syncthreads();  // B DMA + A ds_writes complete

    {  // prefetch next k-tile's A (clamped)
      const int kp = (k0 + 64 < K) ? k0 + 64 : k0;
#pragma unroll
      for (int r = 0; r < 2; r++)
#pragma unroll
        for (int hf = 0; hf < 2; hf++) {
          ax[r * 4 + hf * 2] =
              *(const f32x4*)(Xg + (long)r * 64 * K + kp + hf * 32);
          ax[r * 4 + hf * 2 + 1] =
              *(const f32x4*)(Xg + (long)r * 64 * K + kp + hf * 32 + 4);
        }
    }

#pragma unroll
    for (int hf = 0; hf < 2; hf++) {
      bf16x8 a[4], b[4];
#pragma unroll
      for (int ii = 0; ii < 4; ii++)
        a[ii] = ldsld8(&As[hf][(wr * 64 + ii * 16 + lane15) * 32 + quad * 8]);
#pragma unroll
      for (int j = 0; j < 4; j++)
        b[j] = ldsld8(&Bs[hf][(wc * 64 + j * 16 + lane15) * 32 + quad * 8]);
#pragma unroll
      for (int ii = 0; ii < 4; ii++)
#pragma unroll
        for (int j = 0; j < 4; j++) acc[ii][j] = mfma16(a[ii], b[j], acc[ii][j]);
    }
  }

  __syncthreads();  // K-loop LDS reads done; reuse smem for C staging

  if (col0 >= 1024) {
    // V part: stage TRANSPOSED (+ within-32 s-perm) -> Cs[d][perm(s_local)]
#pragma unroll
    for (int ii = 0; ii < 4; ii++)
#pragma unroll
      for (int j = 0; j < 4; j++) {
        const int d = wc * 64 + j * 16 + lane15;
        const int sl = wr * 64 + ii * 16 + quad * 4;
        const int psl =
            (sl & ~31) | (((sl >> 2) & 3) << 3) | (((sl >> 4) & 1) << 2);
        u32x2 pr;
        pr[0] = pk2(acc[ii][j][0], acc[ii][j][1]);
        pr[1] = pk2(acc[ii][j][2], acc[ii][j][3]);
        *(u16x4*)&Cs[d * LDC + psl] = __builtin_bit_cast(u16x4, pr);
      }
    __syncthreads();
    // coalesced: each vT d-row segment is 128 u16 = 256B contiguous
    const long bb = row0 >> 11;
    const int s0g = (int)(row0 & 2047);
    const int rr = t >> 4, cc = (t & 15) * 8;
#pragma unroll
    for (int p = 0; p < 8; p++) {
      const int d = p * 16 + rr;
      *(u16x8*)(vT + ((bb * 512 + col0 - 1024 + d) * 2048L) + s0g + cc) =
          *(const u16x8*)&Cs[d * LDC + cc];
    }
  } else {
    // Q/K part: stage row-major bf16 (q cols pre-scaled for attn's exp2)
#pragma unroll
    for (int ii = 0; ii < 4; ii++)
#pragma unroll
      for (int j = 0; j < 4; j++) {
        const int c = wc * 64 + j * 16 + lane15;
        const float sc = (col0 + c < 512) ? 0.18033688f : 1.0f;
#pragma unroll
        for (int r = 0; r < 4; r++) {
          const int rw = wr * 64 + ii * 16 + quad * 4 + r;
          Cs[rw * LDC + c] = f2b(acc[ii][j][r] * sc);
        }
      }
    __syncthreads();
    const int rr = t >> 4, cc = (t & 15) * 8;
#pragma unroll
    for (int p = 0; p < 8; p++) {
      const int rw = p * 16 + rr;
      *(u16x8*)(qk + (row0 + rw) * 1024L + col0 + cc) =
          *(const u16x8*)&Cs[rw * LDC + cc];
    }
  }
}

// ---------------------------------------------------------------------------
// gemm3: C[M,512](fp32) = A[M,512](bf16) @ Bt[512,512](fp32)^T + bias.
// BM=128, BN=64, BK=64; XCD-swizzled. LDS-staged fp32 epilogue. (R6-exact)
// ---------------------------------------------------------------------------
__global__ void gemm_b64(const u16* __restrict__ A, const float* __restrict__ Bt,
                         const float* __restrict__ bias, float* __restrict__ C,
                         int N, int K) {
  __shared__ __align__(16) u16 smem[17408];  // 34816 B
  auto As = (u16(*)[128 * 32])smem;          // As[2][4096]
  auto Bs = (u16(*)[64 * 32])(smem + 8192);  // Bs[2][2048]
  float* Cs = (float*)smem;                  // epilogue tile 128 x 68 f32
  constexpr int LDCF = 68;

  const int t = threadIdx.x, lane = t & 63, w = t >> 6;
  const int lane15 = lane & 15, quad = lane >> 4;
  const int wr = w >> 1, wc = w & 1;

  const int i = blockIdx.x;
  const int rt = (i & 7) | (((i >> 3) & 7) << 3);
  const int ct = i >> 6;
  const long row0 = (long)rt * 128;
  const int col0 = ct * 64;

  const int srow = w * 16 + (lane >> 2);
  const int scol = (lane & 3) * 8;
  const u16* Ag = A + (row0 + srow) * (long)K + scol;

  const int brow = t >> 2, bc = (t & 3) * 16;
  const float* Bg = Bt + (long)(col0 + brow) * K + bc;
  u16* BsD = &Bs[bc >> 5][brow * 32 + (bc & 31)];

  f32x4 acc[4][2];
#pragma unroll
  for (int ii = 0; ii < 4; ii++)
#pragma unroll
    for (int j = 0; j < 2; j++) acc[ii][j] = (f32x4)(0.0f);

  f32x4 q0 = *(const f32x4*)Bg, q1 = *(const f32x4*)(Bg + 4);
  f32x4 q2 = *(const f32x4*)(Bg + 8), q3 = *(const f32x4*)(Bg + 12);

  for (int k0 = 0; k0 < K; k0 += 64) {
    __syncthreads();
#pragma unroll
    for (int r = 0; r < 2; r++)
#pragma unroll
      for (int hf = 0; hf < 2; hf++)
        async16(Ag + (long)r * 64 * K + k0 + hf * 32,
                &As[hf][(r * 64 + w * 16) * 32]);
    lst8(BsD, pack8(q0, q1));
    lst8(BsD + 8, pack8(q2, q3));
    __syncthreads();

    {
      const int kp = (k0 + 64 < K) ? k0 + 64 : k0;
      q0 = *(const f32x4*)(Bg + kp);     q1 = *(const f32x4*)(Bg + kp + 4);
      q2 = *(const f32x4*)(Bg + kp + 8); q3 = *(const f32x4*)(Bg + kp + 12);
    }

#pragma unroll
    for (int hf = 0; hf < 2; hf++) {
      bf16x8 a[4], b[2];
#pragma unroll
      for (int ii = 0; ii < 4; ii++)
        a[ii] = ldsld8(&As[hf][(wr * 64 + ii * 16 + lane15) * 32 + quad * 8]);
#pragma unroll
      for (int j = 0; j < 2; j++)
        b[j] = ldsld8(&Bs[hf][(wc * 32 + j * 16 + lane15) * 32 + quad * 8]);
#pragma unroll
      for (int ii = 0; ii < 4; ii++)
#pragma unroll
        for (int j = 0; j < 2; j++) acc[ii][j] = mfma16(a[ii], b[j], acc[ii][j]);
    }
  }

  __syncthreads();  // reuse smem for C staging
#pragma unroll
  for (int ii = 0; ii < 4; ii++)
#pragma unroll
    for (int j = 0; j < 2; j++) {
      const int c = wc * 32 + j * 16 + lane15;
      const float bv = bias[col0 + c];
#pragma unroll
      for (int r = 0; r < 4; r++) {
        const int rw = wr * 64 + ii * 16 + quad * 4 + r;
        Cs[rw * LDCF + c] = acc[ii][j][r] + bv;
      }
    }
  __syncthreads();
  const int rr = t >> 4, cc = (t & 15) * 4;
#pragma unroll
  for (int p = 0; p < 8; p++) {
    const int rw = p * 16 + rr;
    *(f32x4*)(C + (row0 + rw) * (long)N + col0 + cc) =
        *(const f32x4*)&Cs[rw * LDCF + cc];
  }
}

// ---------------------------------------------------------------------------
// attn_v9 (R6-exact): 8-wave (512-thread) blocks over (b, h, 128-q). Wave
// group half=w>>2 processes s-tiles [half*(qb+1), (half+1)*(qb+1)) — equal
// halves. Per 4-wave group: own double-buffered K/V LDS, q=32/wave, swapped
// QK^T, in-register P, lsum-by-MFMA, setprio. End: half-1 dumps unnormalized
// O/lsum into dead K-buffer LDS; half-0 adds, divides once, stores bf16.
// ---------------------------------------------------------------------------
__global__ void __launch_bounds__(512, 4)
attn_v9(const u16* __restrict__ qk, const u16* __restrict__ vT,
        u16* __restrict__ out) {
  constexpr int T = 2048, LDQ = 1024;
  __shared__ __align__(16) u16 Ks[2][2][64 * 72];  // [half][buf]
  __shared__ __align__(16) u16 Vs[2][2][64 * 72];

  const int t = threadIdx.x, lane = t & 63, w = t >> 6;
  const int lane15 = lane & 15, quad = lane >> 4;
  const int half = w >> 2, wl = w & 3;

  const int i = blockIdx.x;
  int qb = i & 15;
  if (i >= 256) qb = 15 - qb;  // big+small block pairing
  const int h = (i >> 4) & 7;
  const int b = (i >> 7) & 3;
  const long baseq = (long)b * T * LDQ;
  const u16* vTb = vT + ((long)b * 512 + h * 64) * 2048;  // rows d, stride 2048

  // Q fragments for two 16-q strips (q = qb*128 + wl*32 + {0,16} + lane15);
  // both halves load the same q rows (they split s, not q).
  const u16* gq =
      qk + baseq + (long)(qb * 128 + wl * 32 + lane15) * LDQ + h * 64 + quad * 8;
  const bf16x8 qa0 = __builtin_bit_cast(bf16x8, *(const u16x8*)gq);
  const bf16x8 qa1 = __builtin_bit_cast(bf16x8, *(const u16x8*)(gq + 32));
  const bf16x8 qc0 = __builtin_bit_cast(bf16x8, *(const u16x8*)(gq + 16 * LDQ));
  const bf16x8 qc1 =
      __builtin_bit_cast(bf16x8, *(const u16x8*)(gq + 16 * LDQ + 32));

  const int th = t & 255;                        // thread within the half
  const int srow = th >> 3, sc8 = (th & 7) * 8;  // staging rows {srow, srow+32}
  const int nsbh = qb + 1;                       // tiles per half
  const int s0 = half * nsbh;                    // first abs tile of this half
  const int sbd = 2 * qb + (wl >> 1);            // wave's diagonal abs tile

  const u16* gk = qk + baseq + (long)(s0 * 64 + srow) * LDQ + 512 + h * 64 + sc8;
  const u16* gv = vTb + (long)srow * 2048 + s0 * 64 + sc8;

  u16x8 kr0, kr1, vr0, vr1;
  kr0 = gld8(gk); kr1 = gld8(gk + (long)32 * LDQ);
  vr0 = gld8(gv); vr1 = gld8(gv + (long)32 * 2048);
  lst8(&Ks[half][0][srow * 72 + sc8], kr0);
  lst8(&Ks[half][0][(srow + 32) * 72 + sc8], kr1);
  lst8(&Vs[half][0][srow * 72 + sc8], vr0);
  lst8(&Vs[half][0][(srow + 32) * 72 + sc8], vr1);
  if (nsbh > 1) { gk += (long)64 * LDQ; gv += 64; }
  kr0 = gld8(gk); kr1 = gld8(gk + (long)32 * LDQ);
  vr0 = gld8(gv); vr1 = gld8(gv + (long)32 * 2048);

  f32x4 o0[4], o1[4], lsum0 = (f32x4)(0.0f), lsum1 = (f32x4)(0.0f);
#pragma unroll
  for (int j = 0; j < 4; j++) { o0[j] = (f32x4)(0.0f); o1[j] = (f32x4)(0.0f); }

  const bf16x8 ones = __builtin_bit_cast(bf16x8, (u16x8)((u16)0x3F80));
  const int ql0 = ((wl & 1) << 5) + lane15;  // strip0 q, tile-local, on diag

  for (int it = 0; it < nsbh; ++it) {
    const u16* Kc = Ks[half][it & 1];
    const u16* Vc = Vs[half][it & 1];
    u16* Kn = Ks[half][(it + 1) & 1];
    u16* Vn = Vs[half][(it + 1) & 1];

    __syncthreads();  // buf[it&1] writes visible; buf[(it+1)&1] readers done

    // stage tile it+1 into the other buffer
    lst8(&Kn[srow * 72 + sc8], kr0);
    lst8(&Kn[(srow + 32) * 72 + sc8], kr1);
    lst8(&Vn[srow * 72 + sc8], vr0);
    lst8(&Vn[(srow + 32) * 72 + sc8], vr1);

    // prefetch tile it+2 (clamped) into regs
    if (it + 2 < nsbh) { gk += (long)64 * LDQ; gv += 64; }
    kr0 = gld8(gk); kr1 = gld8(gk + (long)32 * LDQ);
    vr0 = gld8(gv); vr1 = gld8(gv + (long)32 * 2048);

    const int sb = s0 + it;  // absolute s-tile
    if (sb <= sbd) {         // tiles past the wave's diagonal are fully masked
      __builtin_amdgcn_s_setprio(1);
      // S^T strips: K fragments feed both q-strips
      f32x4 sf0[4], sf1[4];
#pragma unroll
      for (int j = 0; j < 4; j++) {
        const bf16x8 k0 = ldsld8(&Kc[(j * 16 + lane15) * 72 + quad * 8]);
        const bf16x8 k1 = ldsld8(&Kc[(j * 16 + lane15) * 72 + quad * 8 + 32]);
        sf0[j] = mfma16(k1, qa1, mfma16(k0, qa0, (f32x4)(0.0f)));
        sf1[j] = mfma16(k1, qc1, mfma16(k0, qc0, (f32x4)(0.0f)));
      }

#pragma unroll
      for (int j = 0; j < 4; j++)
#pragma unroll
        for (int r = 0; r < 4; r++) {
          sf0[j][r] = exp2f(sf0[j][r]);
          sf1[j][r] = exp2f(sf1[j][r]);
        }
      if (sb == sbd) {  // causal zeroing, this wave's diagonal tile only
#pragma unroll
        for (int j = 0; j < 4; j++)
#pragma unroll
          for (int r = 0; r < 4; r++) {
            const int sl = j * 16 + quad * 4 + r;
            if (sl > ql0) sf0[j][r] = 0.0f;
            if (sl > ql0 + 16) sf1[j][r] = 0.0f;
          }
      }

      // pack P -> A-fragments in-register (k-order matches vT's s-perm)
      u32x4 w0, w1, w2, w3;
      w0[0] = pk2(sf0[0][0], sf0[0][1]); w0[1] = pk2(sf0[0][2], sf0[0][3]);
      w0[2] = pk2(sf0[1][0], sf0[1][1]); w0[3] = pk2(sf0[1][2], sf0[1][3]);
      w1[0] = pk2(sf0[2][0], sf0[2][1]); w1[1] = pk2(sf0[2][2], sf0[2][3]);
      w1[2] = pk2(sf0[3][0], sf0[3][1]); w1[3] = pk2(sf0[3][2], sf0[3][3]);
      w2[0] = pk2(sf1[0][0], sf1[0][1]); w2[1] = pk2(sf1[0][2], sf1[0][3]);
      w2[2] = pk2(sf1[1][0], sf1[1][1]); w2[3] = pk2(sf1[1][2], sf1[1][3]);
      w3[0] = pk2(sf1[2][0], sf1[2][1]); w3[1] = pk2(sf1[2][2], sf1[2][3]);
      w3[2] = pk2(sf1[3][0], sf1[3][1]); w3[3] = pk2(sf1[3][2], sf1[3][3]);
      const bf16x8 pa0 = __builtin_bit_cast(bf16x8, w0);
      const bf16x8 pa1 = __builtin_bit_cast(bf16x8, w1);
      const bf16x8 pc0 = __builtin_bit_cast(bf16x8, w2);
      const bf16x8 pc1 = __builtin_bit_cast(bf16x8, w3);

      // O += P @ V; V fragments feed both strips
#pragma unroll
      for (int j = 0; j < 4; j++) {
        const int d0 = (j * 16 + lane15) * 72;
        const bf16x8 v0 = ldsld8(&Vc[d0 + quad * 8]);
        const bf16x8 v1 = ldsld8(&Vc[d0 + quad * 8 + 32]);
        o0[j] = mfma16(pa1, v1, mfma16(pa0, v0, o0[j]));
        o1[j] = mfma16(pc1, v1, mfma16(pc0, v0, o1[j]));
      }
      // row-sums: C[m][*] = sum_k P[m][k]; lands at row m = quad*4+r
      lsum0 = mfma16(pa1, ones, mfma16(pa0, ones, lsum0));
      lsum1 = mfma16(pc1, ones, mfma16(pc0, ones, lsum1));
      __builtin_amdgcn_s_setprio(0);
    }
  }

  // -------- intra-block combine (pure sums; no rescale needed) --------
  __syncthreads();  // all K/V LDS reads done -> buffers reusable
  float* cmb = (float*)&Ks[0][0][0];  // 128 q x 64 d fp32 = 32 KB (fits in Ks)
  float* cl = (float*)&Vs[0][0][0];   // 128 fp32 row-sums

  if (half == 1) {
    const int q0 = wl * 32 + quad * 4;
#pragma unroll
    for (int j = 0; j < 4; j++)
#pragma unroll
      for (int r = 0; r < 4; r++) {
        cmb[(q0 + r) * 64 + j * 16 + lane15] = o0[j][r];
        cmb[(q0 + 16 + r) * 64 + j * 16 + lane15] = o1[j][r];
      }
    if (lane15 == 0) {
#pragma unroll
      for (int r = 0; r < 4; r++) {
        cl[q0 + r] = lsum0[r];
        cl[q0 + 16 + r] = lsum1[r];
      }
    }
  }
  __syncthreads();

  if (half == 0) {
    const int q0 = wl * 32 + quad * 4;
    f32x4 inv0, inv1;
#pragma unroll
    for (int r = 0; r < 4; r++) {
      inv0[r] = 1.0f / (lsum0[r] + cl[q0 + r]);
      inv1[r] = 1.0f / (lsum1[r] + cl[q0 + 16 + r]);
    }
    const long orow0 = (long)b * T + qb * 128 + wl * 32;
#pragma unroll
    for (int j = 0; j < 4; j++)
#pragma unroll
      for (int r = 0; r < 4; r++) {
        const float a0 = o0[j][r] + cmb[(q0 + r) * 64 + j * 16 + lane15];
        const float a1 = o1[j][r] + cmb[(q0 + 16 + r) * 64 + j * 16 + lane15];
        const long rr = orow0 + quad * 4 + r;
        out[rr * 512 + h * 64 + j * 16 + lane15] = f2b(a0 * inv0[r]);
        out[(rr + 16) * 512 + h * 64 + j * 16 + lane15] = f2b(a1 * inv1[r]);
      }
  }
}

// ---------------------------------------------------------------------------
extern "C" void kernel_launch(void* const* d_in, const int* in_sizes, int n_in,
                              void* d_out, int out_size, void* d_ws, size_t ws_size,
                              hipStream_t stream) {
  const float* x      = (const float*)d_in[0];  // [4,2048,512] fp32
  const float* w_qkv  = (const float*)d_in[1];  // [1536,512]  fp32
  const float* w_proj = (const float*)d_in[2];  // [512,512]   fp32
  const float* b_proj = (const float*)d_in[3];  // [512]       fp32
  float* out = (float*)d_out;                   // [4,2048,512] fp32

  u16* qk = (u16*)d_ws;                   // [8192 x 1024] bf16 = 16 MiB (Q|K)
  u16* vT = qk + (size_t)8192 * 1024;     // [4 x 512 x 2048] bf16 = 8 MiB
  u16* ao = vT + (size_t)4 * 512 * 2048;  // [8192 x 512] bf16 = 8 MiB
  u16* wqb = (u16*)d_out;                 // w_qkv bf16 parked in d_out

  // [0] convert w_qkv to bf16 (x conversion fused into gemm_bb)
  cvt_w<<<384, 256, 0, stream>>>(w_qkv, wqb);
  // [1] qkv projection: qk + transposed/permuted vT (x converted inline)
  gemm_bb<<<768, 256, 0, stream>>>(x, wqb, qk, vT, 512);
  // [2] causal flash attention
  attn_v9<<<512, 512, 0, stream>>>(qk, vT, ao);
  // [3] output projection + bias -> fp32 d_out
  gemm_b64<<<512, 256, 0, stream>>>(ao, w_proj, b_proj, out, 512, 512);
}